// Round 3
// baseline (3226.131 us; speedup 1.0000x reference)
//
#include <hip/hip_runtime.h>

#define NT 131072
#define ED 128
#define KCB 1024
#define NQ 4

#define MT 64               // tokens per block
#define NCH 64              // codes per chunk
#define NCHUNKS (KCB / NCH) // 16
#define RP 132              // Rs row pitch (floats)
#define CP 68               // Cs row pitch (floats)

// ---------------------------------------------------------------------------
// prep: cnorm[c] = np.sum(cb*cb, axis=1) emulated in fp32 (numpy pairwise n=128:
// 8 accumulators stride-8, tree combine). Also zero the loss slot.
// ---------------------------------------------------------------------------
__global__ void prep_kernel(const float* __restrict__ cb,
                            float* __restrict__ cnorm,
                            float* __restrict__ loss_slot) {
#pragma clang fp contract(off)
    int c = blockIdx.x * 256 + threadIdx.x;   // 0..4095
    if (blockIdx.x == 0 && threadIdx.x == 0) loss_slot[0] = 0.0f;
    const float* row = cb + (size_t)c * ED;
    float r8[8];
#pragma unroll
    for (int m = 0; m < 8; ++m) { float v = row[m]; r8[m] = v * v; }
    for (int i = 8; i < ED; i += 8) {
#pragma unroll
        for (int m = 0; m < 8; ++m) {
            float v = row[i + m];
            float p = v * v;          // rounded product (no contraction)
            r8[m] = r8[m] + p;        // rounded add
        }
    }
    cnorm[c] = ((r8[0] + r8[1]) + (r8[2] + r8[3]))
             + ((r8[4] + r8[5]) + (r8[6] + r8[7]));
}

// ---------------------------------------------------------------------------
// fused 4-stage RVQ, numpy-fp32-exact scoring:
//   d_j = fl32( fl32(S - 2*M_j) + n_j ),  M_j = sequential fp32 FMA over k
//   argmin ties -> lowest index
//   quant = fl(r + fl(q - r)); r_new = fl(r - quant); x_q = seq sum of quant
// out: [0, NT*ED) x_q | [NT*ED] loss | [NT*ED+1 ...) indices (as f32)
// ---------------------------------------------------------------------------
__global__ __launch_bounds__(256) void rvq_kernel(const float* __restrict__ x,
                                                  const float* __restrict__ cb,
                                                  const float* __restrict__ cnorm,
                                                  float* __restrict__ d_out) {
#pragma clang fp contract(off)
    __shared__ float Rs[MT * RP];                       // 33792 B residual tile
    __shared__ __align__(16) char csraw[NCH * CP * 4];  // 17408 B: Cs | red bufs
    __shared__ int    selS[MT];
    __shared__ float  Ss[MT];
    __shared__ double lossW[4];

    float* Cs   = (float*)csraw;                 // [NCH][CP]
    float* redS = (float*)csraw;                 // [16 entries][64 tokens]
    int*   redI = (int*)(csraw + 16 * 64 * 4);   // [16 entries][64 tokens]

    const int tid = threadIdx.x;
    const int tx = tid & 15;      // code-dim lane
    const int ty = tid >> 4;      // token-dim lane
    const int t0 = blockIdx.x * MT;

    // stage residual = x tile into LDS
#pragma unroll
    for (int it = 0; it < 8; ++it) {
        int flat = it * 256 + tid;          // 2048 float4
        int row = flat >> 5, c4 = flat & 31;
        float4 v = *(const float4*)(x + (size_t)(t0 + row) * ED + (c4 << 2));
        *(float4*)(&Rs[row * RP + (c4 << 2)]) = v;
    }

    // x_q accumulator in registers: thread (t=tid>>2, qq=tid&3) owns components
    // [qq*32, qq*32+32) of token t — same mapping as the residual update.
    float4 xq[8];
#pragma unroll
    for (int u = 0; u < 8; ++u) { xq[u].x = 0.f; xq[u].y = 0.f; xq[u].z = 0.f; xq[u].w = 0.f; }

    double lossTot = 0.0;

    for (int q = 0; q < NQ; ++q) {
        const float* cbq = cb + (size_t)q * KCB * ED;

        __syncthreads();   // Rs current (initial staging or previous update)

        // S_t = np.sum(r*r, axis=1) — numpy pairwise (order is argmin-invariant
        // anyway: uniform per-token offset on the d-grid preserves order+ties)
        if (tid < MT) {
            const float* rr = &Rs[tid * RP];
            float r8[8];
#pragma unroll
            for (int m = 0; m < 8; ++m) { float v = rr[m]; r8[m] = v * v; }
            for (int i = 8; i < ED; i += 8) {
#pragma unroll
                for (int m = 0; m < 8; ++m) {
                    float v = rr[i + m];
                    float p = v * v;
                    r8[m] = r8[m] + p;
                }
            }
            Ss[tid] = ((r8[0] + r8[1]) + (r8[2] + r8[3]))
                    + ((r8[4] + r8[5]) + (r8[6] + r8[7]));
        }

        // per-thread running first-min for 4 tokens (t = ty + 16*i)
        float s1[4];
        int   i1[4];
#pragma unroll
        for (int i = 0; i < 4; ++i) { s1[i] = 1e30f; i1[i] = 0; }

        for (int cc = 0; cc < NCHUNKS; ++cc) {
            float acc[4][4];
#pragma unroll
            for (int i = 0; i < 4; ++i)
#pragma unroll
                for (int j = 0; j < 4; ++j) acc[i][j] = 0.f;

            // M: ONE sequential fp32 FMA chain over k=0..127 (matches BLAS
            // microkernel: single accumulator, k ascending, fused multiply-add)
            for (int ks = 0; ks < 2; ++ks) {
                __syncthreads();   // protect Cs/red region from previous readers
#pragma unroll
                for (int it = 0; it < 4; ++it) {
                    int flat = it * 256 + tid;      // 1024 float4
                    int row = flat >> 4, c4 = flat & 15;
                    float4 v = *(const float4*)(cbq + (size_t)(cc * NCH + row) * ED
                                                + (ks << 6) + (c4 << 2));
                    *(float4*)(&Cs[row * CP + (c4 << 2)]) = v;
                }
                __syncthreads();

                const float* rb  = &Rs[ty * RP + (ks << 6)];
                const float* cbs = &Cs[tx * CP];
#pragma unroll
                for (int kk = 0; kk < 16; ++kk) {
                    float4 a0 = *(const float4*)(rb + 0 * 16 * RP + (kk << 2));
                    float4 a1 = *(const float4*)(rb + 1 * 16 * RP + (kk << 2));
                    float4 a2 = *(const float4*)(rb + 2 * 16 * RP + (kk << 2));
                    float4 a3 = *(const float4*)(rb + 3 * 16 * RP + (kk << 2));
                    float4 b0 = *(const float4*)(cbs + 0 * 16 * CP + (kk << 2));
                    float4 b1 = *(const float4*)(cbs + 1 * 16 * CP + (kk << 2));
                    float4 b2 = *(const float4*)(cbs + 2 * 16 * CP + (kk << 2));
                    float4 b3 = *(const float4*)(cbs + 3 * 16 * CP + (kk << 2));
#define DOT4(A, I, B, J)                                            \
                    acc[I][J] = fmaf(A.x, B.x, acc[I][J]);          \
                    acc[I][J] = fmaf(A.y, B.y, acc[I][J]);          \
                    acc[I][J] = fmaf(A.z, B.z, acc[I][J]);          \
                    acc[I][J] = fmaf(A.w, B.w, acc[I][J]);
                    DOT4(a0, 0, b0, 0) DOT4(a0, 0, b1, 1) DOT4(a0, 0, b2, 2) DOT4(a0, 0, b3, 3)
                    DOT4(a1, 1, b0, 0) DOT4(a1, 1, b1, 1) DOT4(a1, 1, b2, 2) DOT4(a1, 1, b3, 3)
                    DOT4(a2, 2, b0, 0) DOT4(a2, 2, b1, 1) DOT4(a2, 2, b2, 2) DOT4(a2, 2, b3, 3)
                    DOT4(a3, 3, b0, 0) DOT4(a3, 3, b1, 1) DOT4(a3, 3, b2, 2) DOT4(a3, 3, b3, 3)
#undef DOT4
                }
            }

            // d = fl(fl(S - 2M) + n) — BOTH roundings on the ulp(128) grid,
            // exactly as numpy. This is what creates the grid-ties the ref has.
#pragma unroll
            for (int j = 0; j < 4; ++j) {
                int code = cc * NCH + tx + (j << 4);
                float cn = cnorm[q * KCB + code];
#pragma unroll
                for (int i = 0; i < 4; ++i) {
                    float twoM = acc[i][j] + acc[i][j];        // exact x2
                    float t1 = Ss[ty + (i << 4)] - twoM;       // rounded
                    float s  = t1 + cn;                        // rounded
                    if (s < s1[i]) { s1[i] = s; i1[i] = code; }  // strict <, codes
                }                                                 // ascend: first-min
            }
        }

        // ------- cross-thread first-min reduction (red bufs alias Cs) -------
        __syncthreads();   // all compute reads of Cs done
#pragma unroll
        for (int i = 0; i < 4; ++i) {
            int t = ty + (i << 4);
            redS[tx * 64 + t] = s1[i];
            redI[tx * 64 + t] = i1[i];
        }
        __syncthreads();

        if (tid < MT) {
            int t = tid;
            float b1 = 1e30f;
            int   j1 = 0x7fffffff;
            for (int e = 0; e < 16; ++e) {
                float s  = redS[e * 64 + t];
                int   id = redI[e * 64 + t];
                if (s < b1 || (s == b1 && id < j1)) { b1 = s; j1 = id; }
            }
            selS[t] = j1;
            d_out[(size_t)NT * ED + 1 + (size_t)(t0 + t) * NQ + q] = (float)j1;
        }
        __syncthreads();

        // ------- straight-through chain, numpy-exact fp32 -------
        {
            int t = tid >> 2, qq = tid & 3;
            int sel = selS[t];
            const float4* crow = (const float4*)(cbq + (size_t)sel * ED);
#pragma unroll
            for (int u = 0; u < 8; ++u) {
                int c4 = (qq << 3) + u;
                float4 qv = crow[c4];
                float4 r = *(float4*)(&Rs[t * RP + (c4 << 2)]);
                float4 d1, qt, rn;
                d1.x = qv.x - r.x;  qt.x = r.x + d1.x;  rn.x = r.x - qt.x;
                d1.y = qv.y - r.y;  qt.y = r.y + d1.y;  rn.y = r.y - qt.y;
                d1.z = qv.z - r.z;  qt.z = r.z + d1.z;  rn.z = r.z - qt.z;
                d1.w = qv.w - r.w;  qt.w = r.w + d1.w;  rn.w = r.w - qt.w;
                *(float4*)(&Rs[t * RP + (c4 << 2)]) = rn;
                xq[u].x = xq[u].x + qt.x;  xq[u].y = xq[u].y + qt.y;
                xq[u].z = xq[u].z + qt.z;  xq[u].w = xq[u].w + qt.w;
                lossTot += (double)rn.x * rn.x + (double)rn.y * rn.y
                         + (double)rn.z * rn.z + (double)rn.w * rn.w;
            }
        }
        // next stage's top __syncthreads orders Rs writes vs reads
    }

    // x_q = sequential fp32 sum of quantized (accumulated above)
    {
        int t = tid >> 2, qq = tid & 3;
#pragma unroll
        for (int u = 0; u < 8; ++u) {
            int c4 = (qq << 3) + u;
            *(float4*)(d_out + (size_t)(t0 + t) * ED + (c4 << 2)) = xq[u];
        }
    }

    // loss reduce: wave shuffle -> LDS -> one atomic per block
    double l = lossTot;
#pragma unroll
    for (int off = 32; off > 0; off >>= 1) l += __shfl_down(l, off, 64);
    if ((tid & 63) == 0) lossW[tid >> 6] = l;
    __syncthreads();
    if (tid == 0) {
        double s = lossW[0] + lossW[1] + lossW[2] + lossW[3];
        // mean_loss = BETA/(4*N*E) * sum_q ||r_{q+1}||^2
        atomicAdd(d_out + (size_t)NT * ED, (float)(s * (0.25 / (4.0 * (double)NT * ED))));
    }
}

// ---------------------------------------------------------------------------
extern "C" void kernel_launch(void* const* d_in, const int* in_sizes, int n_in,
                              void* d_out, int out_size, void* d_ws, size_t ws_size,
                              hipStream_t stream) {
    const float* x  = (const float*)d_in[0];
    const float* cb = (const float*)d_in[1];
    float* out   = (float*)d_out;
    float* cnorm = (float*)d_ws;  // 4096 floats

    prep_kernel<<<16, 256, 0, stream>>>(cb, cnorm, out + (size_t)NT * ED);
    rvq_kernel<<<NT / MT, 256, 0, stream>>>(x, cb, cnorm, out);
}

// Round 4
// 1451.719 us; speedup vs baseline: 2.2223x; 2.2223x over previous
//
#include <hip/hip_runtime.h>

#define NT 131072
#define ED 128
#define KCB 1024
#define NQ 4

#define MT 128                 // tokens per block
#define NBLK (NT / MT)         // 1024 blocks
#define NCH 64                 // codes per chunk
#define NCHUNKS (KCB / NCH)    // 16
#define AP 136                 // As pitch (bf16 elems)
#define BP 136                 // Bs pitch (bf16 elems)
#define PAIR_CAP 1024
#define MARGIN 1.5e-3f

typedef __attribute__((ext_vector_type(8))) short bf16x8;
typedef __attribute__((ext_vector_type(4))) float f32x4;

// ---- bf16 round-to-nearest-even, returns low 16 bits ----
__device__ __forceinline__ unsigned bf16rne(float f) {
    unsigned u = __float_as_uint(f);
    u += 0x7fffu + ((u >> 16) & 1u);
    return u >> 16;
}
__device__ __forceinline__ unsigned packbf(float a, float b) {
    return bf16rne(a) | (bf16rne(b) << 16);
}
// ---- monotone float<->uint (unsigned compare preserves float order) ----
__device__ __forceinline__ unsigned fmono(float f) {
    unsigned u = __float_as_uint(f);
    return (u & 0x80000000u) ? ~u : (u | 0x80000000u);
}
__device__ __forceinline__ float fmono_inv(unsigned m) {
    unsigned u = (m & 0x80000000u) ? (m & 0x7fffffffu) : ~m;
    return __uint_as_float(u);
}

// ---------------------------------------------------------------------------
// prep: cnorm[c] = np.sum(cb*cb, axis=1) fp32 numpy-pairwise (validated r3);
// zero the loss slot.
// ---------------------------------------------------------------------------
__global__ void prep_kernel(const float* __restrict__ cb,
                            float* __restrict__ cnorm,
                            float* __restrict__ loss_slot) {
#pragma clang fp contract(off)
    int c = blockIdx.x * 256 + threadIdx.x;   // 0..4095
    if (blockIdx.x == 0 && threadIdx.x == 0) loss_slot[0] = 0.0f;
    const float* row = cb + (size_t)c * ED;
    float r8[8];
#pragma unroll
    for (int m = 0; m < 8; ++m) { float v = row[m]; r8[m] = v * v; }
    for (int i = 8; i < ED; i += 8) {
#pragma unroll
        for (int m = 0; m < 8; ++m) {
            float v = row[i + m];
            float p = v * v;
            r8[m] = r8[m] + p;
        }
    }
    cnorm[c] = ((r8[0] + r8[1]) + (r8[2] + r8[3]))
             + ((r8[4] + r8[5]) + (r8[6] + r8[7]));
}

// ---------------------------------------------------------------------------
// per-element straight-through chain step (validated r3): given r and code val
// q: d1=fl(q-r); qt=fl(r+d1); rn=fl(r-qt)
#define CHAIN4(V, C)                                                     \
    { float d1x = (C).x - (V).x, d1y = (C).y - (V).y,                    \
            d1z = (C).z - (V).z, d1w = (C).w - (V).w;                    \
      float qtx = (V).x + d1x, qty = (V).y + d1y,                        \
            qtz = (V).z + d1z, qtw = (V).w + d1w;                        \
      (V).x = (V).x - qtx; (V).y = (V).y - qty;                          \
      (V).z = (V).z - qtz; (V).w = (V).w - qtw; }

// ---------------------------------------------------------------------------
// main fused MFMA RVQ kernel
// out: [0, NT*ED) x_q | [NT*ED] loss | [NT*ED+1 ...) indices (as f32)
// ---------------------------------------------------------------------------
__global__ __launch_bounds__(256) void rvq_mfma(const float* __restrict__ x,
                                                const float* __restrict__ cb,
                                                const float* __restrict__ cnorm,
                                                float* __restrict__ d_out) {
#pragma clang fp contract(off)
    __shared__ __align__(16) unsigned short As[MT * AP];    // 34816 B bf16 tokens
    __shared__ __align__(16) unsigned short Bs[NCH * BP];   // 17408 B bf16 codes
    __shared__ float    cnS[NCH];
    __shared__ unsigned minbuf[MT];
    __shared__ unsigned long long selMin[MT];
    __shared__ float    Ss[MT];
    __shared__ int      selSh[MT * NQ];
    __shared__ unsigned pairList[PAIR_CAP];
    __shared__ int      pairCnt;
    __shared__ double   lossW[4];

    const int tid  = threadIdx.x;
    const int lane = tid & 63;
    const int wid  = tid >> 6;     // wave 0..3 -> tokens [wid*32, wid*32+32)
    const int l15  = lane & 15;
    const int quad = lane >> 4;
    const int t0   = blockIdx.x * MT;

    unsigned* AsU = (unsigned*)As;
    unsigned* BsU = (unsigned*)Bs;

    double lossTot = 0.0;

    for (int q = 0; q < NQ; ++q) {
        const float* cbq = cb + (size_t)q * KCB * ED;

        // ---- stage top: resets ----
        if (tid < MT) { minbuf[tid] = 0xFFFFFFFFu; selMin[tid] = ~0ull; }
        if (tid == 0) pairCnt = 0;
        __syncthreads();   // also orders prev-stage As reads vs writes below

        // ---- S (numpy pairwise) + As bf16 conversion, residual recomputed
        //      from x + selection history (exact fp32 chain, r3-validated) ----
        if (tid < MT) {
            int t = tid;
            const float* xr = x + (size_t)(t0 + t) * ED;
            const float* hp[3];
            for (int p2 = 0; p2 < q; ++p2)
                hp[p2] = cb + ((size_t)p2 * KCB + selSh[t * NQ + p2]) * ED;
            float r8[8];
#pragma unroll
            for (int m = 0; m < 8; ++m) r8[m] = 0.f;
#pragma unroll 4
            for (int i = 0; i < 32; ++i) {
                float4 v = *(const float4*)(xr + (i << 2));
                for (int p2 = 0; p2 < q; ++p2) {
                    float4 c = *(const float4*)(hp[p2] + (i << 2));
                    CHAIN4(v, c)
                }
                // pack to As (bf16 RNE)
                AsU[t * (AP / 2) + 2 * i]     = packbf(v.x, v.y);
                AsU[t * (AP / 2) + 2 * i + 1] = packbf(v.z, v.w);
                // numpy 8-acc squares: k=4i+j -> m=(4i+j)&7
                int base = (i & 1) << 2;
                float px = v.x * v.x, py = v.y * v.y,
                      pz = v.z * v.z, pw = v.w * v.w;
                r8[base + 0] = r8[base + 0] + px;
                r8[base + 1] = r8[base + 1] + py;
                r8[base + 2] = r8[base + 2] + pz;
                r8[base + 3] = r8[base + 3] + pw;
            }
            Ss[t] = ((r8[0] + r8[1]) + (r8[2] + r8[3]))
                  + ((r8[4] + r8[5]) + (r8[6] + r8[7]));
        }
        __syncthreads();   // As, Ss ready

        // ---- load token (B-operand) fragments once per stage ----
        bf16x8 bfrag[2][4];
#pragma unroll
        for (int tt = 0; tt < 2; ++tt)
#pragma unroll
            for (int ks = 0; ks < 4; ++ks) {
                int tok = wid * 32 + tt * 16 + l15;
                bfrag[tt][ks] = *(const bf16x8*)&As[tok * AP + ks * 32 + quad * 8];
            }

        // ---- chunk loop over 1024 codes ----
        f32x4 acc[4][2];   // [code-tile][token-tile]; holds scores after epilog
        for (int cc = 0; cc <= NCHUNKS; ++cc) {
            // candidate pass for chunk cc-1 (acc holds its scores; minbuf settled)
            if (cc > 0) {
#pragma unroll
                for (int tt = 0; tt < 2; ++tt) {
                    int token = wid * 32 + tt * 16 + l15;
                    float th = fmono_inv(minbuf[token]) + MARGIN;
#pragma unroll
                    for (int ct = 0; ct < 4; ++ct)
#pragma unroll
                        for (int r2 = 0; r2 < 4; ++r2) {
                            float e = acc[ct][tt][r2];
                            if (e <= th) {
                                int code = (cc - 1) * NCH + ct * 16 + quad * 4 + r2;
                                int pos = atomicAdd(&pairCnt, 1);
                                if (pos < PAIR_CAP)
                                    pairList[pos] = ((unsigned)token << 10) | (unsigned)code;
                            }
                        }
                }
            }
            if (cc == NCHUNKS) break;

            // stage Bs chunk (fp32 -> bf16 RNE) + cnorm chunk
            {
                int row = tid >> 2, seg = tid & 3;
                const float* src = cbq + (size_t)(cc * NCH + row) * ED + seg * 32;
                unsigned* dst = BsU + row * (BP / 2) + seg * 16;
#pragma unroll
                for (int j = 0; j < 4; ++j) {
                    float4 a = *(const float4*)(src + j * 8);
                    float4 b = *(const float4*)(src + j * 8 + 4);
                    uint4 w;
                    w.x = packbf(a.x, a.y); w.y = packbf(a.z, a.w);
                    w.z = packbf(b.x, b.y); w.w = packbf(b.z, b.w);
                    *(uint4*)(dst + j * 4) = w;
                }
                if (tid < 16) {
                    float4 cv = *(const float4*)(cnorm + q * KCB + cc * NCH + tid * 4);
                    *(float4*)&cnS[tid * 4] = cv;
                }
            }
            __syncthreads();   // Bs/cnS ready (also fences cand-pass pushes)

            // MFMA: D[code][token] over 64 codes x 32 tokens per wave
#pragma unroll
            for (int ct = 0; ct < 4; ++ct)
#pragma unroll
                for (int tt = 0; tt < 2; ++tt)
                    acc[ct][tt] = (f32x4){0.f, 0.f, 0.f, 0.f};
#pragma unroll
            for (int ks = 0; ks < 4; ++ks) {
                bf16x8 afr[4];
#pragma unroll
                for (int ct = 0; ct < 4; ++ct)
                    afr[ct] = *(const bf16x8*)&Bs[(ct * 16 + l15) * BP + ks * 32 + quad * 8];
#pragma unroll
                for (int ct = 0; ct < 4; ++ct)
#pragma unroll
                    for (int tt = 0; tt < 2; ++tt)
                        acc[ct][tt] = __builtin_amdgcn_mfma_f32_16x16x32_bf16(
                            afr[ct], bfrag[tt][ks], acc[ct][tt], 0, 0, 0);
            }

            // scores e = cn - 2*M~ (approx; exact handled by rescore) + token min
            float tmin[2] = {1e30f, 1e30f};
#pragma unroll
            for (int ct = 0; ct < 4; ++ct)
#pragma unroll
                for (int tt = 0; tt < 2; ++tt)
#pragma unroll
                    for (int r2 = 0; r2 < 4; ++r2) {
                        float m2 = acc[ct][tt][r2];
                        float e = cnS[ct * 16 + quad * 4 + r2] - (m2 + m2);
                        acc[ct][tt][r2] = e;
                        tmin[tt] = fminf(tmin[tt], e);
                    }
#pragma unroll
            for (int tt = 0; tt < 2; ++tt) {
                float v = tmin[tt];
                v = fminf(v, __shfl_xor(v, 16, 64));
                v = fminf(v, __shfl_xor(v, 32, 64));
                if (quad == 0)
                    atomicMin(&minbuf[wid * 32 + tt * 16 + l15], fmono(v));
            }
            __syncthreads();   // minbuf includes chunks <= cc
        }
        __syncthreads();   // all candidate pushes visible

        // ---- exact rescore of candidates (bit-identical to r3 math) ----
        {
            int npair = pairCnt < PAIR_CAP ? pairCnt : PAIR_CAP;
            for (int p = tid; p < npair; p += 256) {
                unsigned pk = pairList[p];
                int t = (pk >> 10) & 127, code = pk & 1023;
                const float* xr = x + (size_t)(t0 + t) * ED;
                const float* cr = cbq + (size_t)code * ED;
                const float* hp[3];
                for (int p2 = 0; p2 < q; ++p2)
                    hp[p2] = cb + ((size_t)p2 * KCB + selSh[t * NQ + p2]) * ED;
                float M = 0.f;
                for (int k = 0; k < ED; k += 4) {
                    float4 v = *(const float4*)(xr + k);
                    for (int p2 = 0; p2 < q; ++p2) {
                        float4 c = *(const float4*)(hp[p2] + k);
                        CHAIN4(v, c)
                    }
                    float4 cv = *(const float4*)(cr + k);
                    M = fmaf(v.x, cv.x, M); M = fmaf(v.y, cv.y, M);
                    M = fmaf(v.z, cv.z, M); M = fmaf(v.w, cv.w, M);
                }
                float t1 = Ss[t] - (M + M);          // rounded (contract off)
                float dd = t1 + cnorm[q * KCB + code];  // rounded
                unsigned long long key =
                    ((unsigned long long)fmono(dd) << 10) | (unsigned)code;
                unsigned long long old = selMin[t];
                while (key < old) {
                    unsigned long long assumed = old;
                    old = atomicCAS(&selMin[t], assumed, key);
                    if (old == assumed) break;
                }
            }
        }
        __syncthreads();

        if (tid < MT) {
            int code = (int)(selMin[tid] & 1023ull);
            selSh[tid * NQ + q] = code;
            d_out[(size_t)NT * ED + 1 + (size_t)(t0 + tid) * NQ + q] = (float)code;
        }
        __syncthreads();
    }

    // ---- epilogue: x_q = x - r4 (exact chain), loss = sum ||r_1..4||^2 ----
    if (tid < MT) {
        int t = tid;
        const float* xr = x + (size_t)(t0 + t) * ED;
        const float* hp[4];
#pragma unroll
        for (int p2 = 0; p2 < NQ; ++p2)
            hp[p2] = cb + ((size_t)p2 * KCB + selSh[t * NQ + p2]) * ED;
        double lo = 0.0;
        for (int k = 0; k < ED; k += 4) {
            float4 v = *(const float4*)(xr + k);
            float4 o = v;
#pragma unroll
            for (int p2 = 0; p2 < NQ; ++p2) {
                float4 c = *(const float4*)(hp[p2] + k);
                CHAIN4(v, c)
                lo += (double)v.x * v.x + (double)v.y * v.y
                    + (double)v.z * v.z + (double)v.w * v.w;
            }
            float4 xq;
            xq.x = o.x - v.x; xq.y = o.y - v.y;
            xq.z = o.z - v.z; xq.w = o.w - v.w;
            *(float4*)(d_out + (size_t)(t0 + t) * ED + k) = xq;
        }
        lossTot = lo;
    }

    // loss reduce: wave shuffle -> LDS -> one atomic per block
    double l = lossTot;
#pragma unroll
    for (int off = 32; off > 0; off >>= 1) l += __shfl_down(l, off, 64);
    if ((tid & 63) == 0) lossW[tid >> 6] = l;
    __syncthreads();
    if (tid == 0) {
        double s = lossW[0] + lossW[1] + lossW[2] + lossW[3];
        // mean_loss = BETA/(4*N*E) * sum_q ||r_{q+1}||^2
        atomicAdd(d_out + (size_t)NT * ED, (float)(s * (0.25 / (4.0 * (double)NT * ED))));
    }
}

// ---------------------------------------------------------------------------
extern "C" void kernel_launch(void* const* d_in, const int* in_sizes, int n_in,
                              void* d_out, int out_size, void* d_ws, size_t ws_size,
                              hipStream_t stream) {
    const float* x  = (const float*)d_in[0];
    const float* cb = (const float*)d_in[1];
    float* out   = (float*)d_out;
    float* cnorm = (float*)d_ws;  // 4096 floats

    prep_kernel<<<16, 256, 0, stream>>>(cb, cnorm, out + (size_t)NT * ED);
    rvq_mfma<<<NBLK, 256, 0, stream>>>(x, cb, cnorm, out);
}